// Round 8
// baseline (27.060 us; speedup 1.0000x reference)
//
#include <hip/hip_runtime.h>
#include <math.h>

#define TPB 1024
#define NDIM 8

typedef float fvec4 __attribute__((ext_vector_type(4)));

__global__ __launch_bounds__(TPB) void vegas_map_kernel(
    const float* __restrict__ u,      // [n, 8] = [nent] float4 entries
    const float* __restrict__ grid,   // [8, gcols]
    float* __restrict__ x_out,        // [n, 8]
    float* __restrict__ lj_out,       // [n]
    int nent, int gcols, float lj_const) // nent = 2*n; lj_const = 8*ln(ninc)
{
    extern __shared__ float lds_grid[];   // 8 * gcols floats (32 KB for gcols=1001)
    const int ninc = gcols - 1;
    const int gtot4 = (NDIM * gcols) >> 2;

    // Stage grid table into LDS (coalesced 16B loads).
    const fvec4* __restrict__ g4 = (const fvec4*)grid;
    fvec4* lds4 = (fvec4*)lds_grid;
    for (int t = threadIdx.x; t < gtot4; t += TPB)
        lds4[t] = g4[t];
    __syncthreads();

    const float fninc = (float)ninc;
    const fvec4* __restrict__ u4 = (const fvec4*)u;
    fvec4* __restrict__ x4 = (fvec4*)x_out;

    // Lane owns ONE float4 entry = 4 dims of one point; entry parity == lane
    // parity (strides are multiples of 64), so the LDS row base is invariant.
    const float* rows = lds_grid + (threadIdx.x & 1) * (4 * gcols);
    const bool is_even = ((threadIdx.x & 1) == 0);

    const int stride = gridDim.x * TPB;
    int e = blockIdx.x * TPB + threadIdx.x;
    if (e >= nent) return;

    // Rotating one-ahead prefetch: always one u-load in flight per wave.
    fvec4 a = u4[e];
    for (; e < nent; ) {
        const int en = e + stride;
        fvec4 nexta;
        const bool more = (en < nent);
        if (more) nexta = u4[en];            // issue BEFORE consuming a

        float uv[4] = {a.x, a.y, a.z, a.w};
        float xv[4];
        float pp = 1.0f;

        #pragma unroll
        for (int k = 0; k < 4; ++k) {
            float un  = uv[k] * fninc;
            int   iu  = (int)un;                 // trunc == floor (un >= 0)
            int   iuc = iu < ninc ? iu : (ninc - 1);
            float du  = un - (float)iuc;         // clamp trick: edge reproduces upper
            const float* row = rows + k * gcols;
            float g0 = row[iuc];
            float g1 = row[iuc + 1];             // adjacent -> ds_read2_b32 pair
            float h  = g1 - g0;                  // == inc bit-exactly
            xv[k] = g0 + h * du;
            pp *= h;                             // partial product over 4 dims
        }

        fvec4 o = {xv[0], xv[1], xv[2], xv[3]};
        x4[e] = o;                               // perfectly coalesced store

        // Adjacent lanes hold the two halves of one point.
        float po = __shfl_xor(pp, 1);
        if (is_even)
            lj_out[e >> 1] = __logf(pp * po) + lj_const;

        if (!more) break;
        a = nexta;
        e = en;
    }
}

extern "C" void kernel_launch(void* const* d_in, const int* in_sizes, int n_in,
                              void* d_out, int out_size, void* d_ws, size_t ws_size,
                              hipStream_t stream) {
    const float* u    = (const float*)d_in[0];   // [N, 8]
    const float* grid = (const float*)d_in[1];   // [8, ninc+1]
    // d_in[2] = inc (recomputed as adjacent grid diffs), d_in[3] = ninc (derived)
    const int n     = in_sizes[0] / NDIM;
    const int gcols = in_sizes[1] / NDIM;        // ninc + 1
    const int ninc  = gcols - 1;
    const int nent  = 2 * n;                     // float4 half-point entries

    float* x_out  = (float*)d_out;
    float* lj_out = (float*)d_out + (size_t)n * NDIM;

    const float lj_const = (float)(NDIM * log((double)ninc));

    int blocks = (nent + TPB - 1) / TPB;
    if (blocks > 512) blocks = 512;              // 2 blocks/CU x 256 CUs = 32 waves/CU
    size_t lds_bytes = (size_t)NDIM * gcols * sizeof(float);

    vegas_map_kernel<<<blocks, TPB, lds_bytes, stream>>>(u, grid, x_out, lj_out,
                                                         nent, gcols, lj_const);
}